// Round 1
// 342.863 us; speedup vs baseline: 1.0183x; 1.0183x over previous
//
#include <hip/hip_runtime.h>

namespace {

constexpr int kB = 16384;
constexpr int kC = 4;
constexpr int kH = 8;
constexpr int kT = 120;
constexpr float kAlpha  = 0.2f;
constexpr float kThresh = 0.5f;

typedef float vf4 __attribute__((ext_vector_type(4)));

__device__ __forceinline__ float fast_tanh(float x) {
    // tanh(x) = 1 - 2/(exp2(2*log2e*x)+1): v_mul + v_exp + v_add + v_rcp + v_fma.
    // x*(f32)(2*log2e) is bit-identical to __expf(x+x)'s (2x)*(f32)log2e.
    float e = __builtin_amdgcn_exp2f(x * 2.8853900817779268f);
    float r = __builtin_amdgcn_rcpf(e + 1.0f);
    return fmaf(-2.0f, r, 1.0f);
}

// DPP lane permutes (full-rate VALU, no LDS).
// quad_perm: xor1=0xB1, xor2=0x4E, xor3=0x1B. row_half_mirror (0x141): lane^7.
template <int CTRL>
__device__ __forceinline__ float dppmov(float x) {
    return __builtin_bit_cast(float, __builtin_amdgcn_mov_dpp(
        __builtin_bit_cast(int, x), CTRL, 0xF, 0xF, true));
}
// lane^4 on the VALU: RHM (^7) then quad_perm[3,2,1,0] (^3) -> ^4.
__device__ __forceinline__ float xor4_dpp(float x) {
    return dppmov<0x1B>(dppmov<0x141>(x));
}
// lane^4 on the LDS pipe (ds_swizzle BitMode: offset=(4<<10)|0x1F).
// Offloads the state exchange from VALU issue slots; no bank conflicts.
__device__ __forceinline__ float xor4_swz(float x) {
    return __builtin_bit_cast(float, __builtin_amdgcn_ds_swizzle(
        __builtin_bit_cast(int, x), 0x101F));
}

// Lane layout: tid = b*8 + half*4 + c.
//   - classes c=0..3 occupy aligned quads (both halves see all 4 classes)
//   - the h-half partner sits at lane^4 (same row of 8)
// Lane owns state rows k = half*4 .. half*4+3 and the matching 16B noise slice.
__global__ __launch_bounds__(256) void acc_rnn_kernel(
    const float* __restrict__ logits,      // [B,C]
    const float* __restrict__ p_iscale,    // [1]
    const float* __restrict__ p_nstd,      // [1]
    const float* __restrict__ ipw_,        // [H,1]
    const float* __restrict__ ipb_,        // [H]
    const float* __restrict__ spw_,        // [H,H]
    const float* __restrict__ cpw_,        // [H,1]
    const float* __restrict__ evw_,        // [1,H]
    const float* __restrict__ evb_,        // [1]
    const float* __restrict__ cbias_,      // [C,H]
    const float* __restrict__ compmat_,    // [C,C]
    const float* __restrict__ noise_,      // [T,B,C,H]
    float* __restrict__ out)               // [B,C]
{
    const int tid  = blockIdx.x * 256 + threadIdx.x;
    const int c    = tid & 3;
    const int half = (tid >> 2) & 1;
    const int kOfs = half << 2;            // own rows k = kOfs..kOfs+3
    const int pid  = ((tid >> 3) << 2) | c;   // b*4 + c

    const float iscale = p_iscale[0];
    const float nstd   = p_nstd[0];
    const float evb    = evb_[0];

    // Noise stream first in program order so the ring loads are the oldest
    // vmem ops only after the (older) weight loads; compiler uses counted waits.
    const vf4* np4 = (const vf4*)noise_;
    const int stepStride = kB * kC * kH / 4;   // 131072
    const int base = (tid & ~7) + ((tid & 3) << 1) + half;

    // Vectorized preamble gather: 13 x dwordx4 instead of 44 scalar dwords.
    float Wown[4][4], Woth[4][4], cpw[4], evw[4], inp[4];
    {
        vf4 cpwv = *(const vf4*)&cpw_[kOfs];
        vf4 evwv = *(const vf4*)&evw_[kOfs];
        vf4 ipwv = *(const vf4*)&ipw_[kOfs];
        vf4 ipbv = *(const vf4*)&ipb_[kOfs];
        vf4 cbv  = *(const vf4*)&cbias_[c * kH + kOfs];
#pragma unroll
        for (int i = 0; i < 4; ++i) {
            const int k = kOfs + i;
            vf4 wo = *(const vf4*)&spw_[k * kH + kOfs];         // own-half cols
            vf4 wx = *(const vf4*)&spw_[k * kH + (kOfs ^ 4)];   // other-half cols
#pragma unroll
            for (int j = 0; j < 4; ++j) { Wown[i][j] = wo[j]; Woth[i][j] = wx[j]; }
            cpw[i] = cpwv[i];
            evw[i] = evwv[i];
        }
        float rl = logits[pid] * iscale;
        rl = rl > 0.0f ? rl : 0.0f;
#pragma unroll
        for (int i = 0; i < 4; ++i)
            inp[i] = fmaf(rl, ipwv[i], ipbv[i] + cbv[i]);
    }

    // comp[c] = sum_{c'} ev[c'] * M[c', c]; quad-xor j partner carries M[c^j, c].
    const float mw0 = compmat_[(c ^ 0) * kC + c];
    const float mw1 = compmat_[(c ^ 1) * kC + c];
    const float mw2 = compmat_[(c ^ 2) * kC + c];
    const float mw3 = compmat_[(c ^ 3) * kC + c];

    float s[4] = {0.0f, 0.0f, 0.0f, 0.0f};
    float ev = evb;                        // ev(state0); carried across steps

    // 8-deep prefetch ring: 8 outstanding 16B loads/lane, 64 KB/CU in flight.
    vf4 nb[8];
#pragma unroll
    for (int j = 0; j < 8; ++j)
        nb[j] = __builtin_nontemporal_load(&np4[j * stepStride + base]);

    // Decision via running max: cnt = #steps before first ev>thresh.
    float mrun = -3.0e38f;
    int   cnt  = 0;

    auto do_step = [&](int t, int j, bool PF) {
        // competition from carried evidence (identical on both halves)
        float e1 = dppmov<0xB1>(ev);
        float e2 = dppmov<0x4E>(ev);
        float e3 = dppmov<0x1B>(ev);
        float comp = fmaf(e1, mw1, ev * mw0) + fmaf(e3, mw3, e2 * mw2);

        float nz[4] = {nb[j].x, nb[j].y, nb[j].z, nb[j].w};
        if (PF)
            nb[j] = __builtin_nontemporal_load(&np4[(t + 8) * stepStride + base]);

        // partner's 4 state rows via lane^4 on the LDS pipe (frees VALU slots)
        float so[4];
#pragma unroll
        for (int i = 0; i < 4; ++i) so[i] = xor4_swz(s[i]);

        float cand[4];
#pragma unroll
        for (int i = 0; i < 4; ++i) {
            float a = fmaf(comp, cpw[i], inp[i]);
            a = fmaf(nz[i], nstd, a);
#pragma unroll
            for (int j2 = 0; j2 < 4; ++j2) a = fmaf(s[j2],  Wown[i][j2], a);
#pragma unroll
            for (int j2 = 0; j2 < 4; ++j2) a = fmaf(so[j2], Woth[i][j2], a);
            cand[i] = fast_tanh(a);
        }

        float evp = 0.0f;
#pragma unroll
        for (int i = 0; i < 4; ++i) {
            s[i] = fmaf(kAlpha, cand[i] - s[i], s[i]);
            evp = fmaf(s[i], evw[i], evp);
        }
        // keep the latency-critical evidence reduction on the VALU (DPP)
        ev = (evp + xor4_dpp(evp)) + evb;

        mrun = fmaxf(mrun, ev);
        cnt += (mrun <= kThresh) ? 1 : 0;
    };

    // Main: prefetch always valid (t+8 <= 119 for t <= 111).
    for (int t0 = 0; t0 < kT - 8; t0 += 8) {   // t0 = 0..104, 14 iters
#pragma unroll
        for (int j = 0; j < 8; ++j) do_step(t0 + j, j, true);
    }
    // Epilogue: t = 112..119, no prefetch.
#pragma unroll
    for (int j = 0; j < 8; ++j) do_step(kT - 8 + j, j, false);

    if (half == 0) {
        // first-cross idx = cnt; (idx+1)*DT clamped to never=1200, then ms->s.
        float tdec = fminf((float)(cnt + 1) * 10.0f, 1200.0f);
        out[pid] = tdec * (1.0f / 1000.0f);
    }
}

}  // namespace

extern "C" void kernel_launch(void* const* d_in, const int* in_sizes, int n_in,
                              void* d_out, int out_size, void* d_ws, size_t ws_size,
                              hipStream_t stream) {
    (void)in_sizes; (void)n_in; (void)d_ws; (void)ws_size; (void)out_size;
    const float* logits   = (const float*)d_in[0];
    const float* iscale   = (const float*)d_in[1];
    const float* nstd     = (const float*)d_in[2];
    const float* ipw      = (const float*)d_in[3];
    const float* ipb      = (const float*)d_in[4];
    const float* spw      = (const float*)d_in[5];
    const float* cpw      = (const float*)d_in[6];
    const float* evw      = (const float*)d_in[7];
    const float* evb      = (const float*)d_in[8];
    const float* cbias    = (const float*)d_in[9];
    const float* compmat  = (const float*)d_in[10];
    const float* noise    = (const float*)d_in[11];
    float* out = (float*)d_out;

    // 2 lanes per (b,c): 131072 threads, 512 blocks (2 blocks/CU).
    dim3 grid(kB * kC * 2 / 256), block(256);
    acc_rnn_kernel<<<grid, block, 0, stream>>>(
        logits, iscale, nstd, ipw, ipb, spw, cpw, evw, evb,
        cbias, compmat, noise, out);
}